// Round 10
// baseline (3412.604 us; speedup 1.0000x reference)
//
#include <hip/hip_runtime.h>
#include <hip/hip_bf16.h>

// LSTM B=32,T=512,D=512,H=1024, persistent kernel.
// R13 = R11 + x-projection hoisted out of the loop as a FUSED PRODUCER
// role, with a runtime ws_size guard (R12's core dump was almost
// certainly workspace overflow at 302MB; guarded now).
//  - XP=1 (ws_size >= ~315MB): grid 256. Blocks 0-63 = lean recurrent
//    loop (h-only MFMAs: 64/wave/step, wreg[16], fully reg-resident).
//    Blocks 64-255 = xproj producers: grid-stride over 16384 (tt,nt)
//    64x64 GEMM tiles of xproj[m=t*32+b][4H] = X@Wx in t-ascending
//    order; per tile: agent-atomic f32 stores -> own-vmcnt drain ->
//    syncthreads -> tid0 fetch_add(counter[tt]). Consumers gate step t
//    on counter[t>>1]==64 (producers run ~4x faster than consumption ->
//    gate open after the first steps; the 137-GFLOP GEMM is ~free).
//    All 256 blocks co-resident: 66KB LDS -> 1 block/CU x 256 CUs.
//  - XP=0 fallback (ws too small): EXACT R11 (passed, 3275us): in-loop
//    x from Xpk, wreg[24], grid 64. No crash possible.
//  - Release/store protocol for h EXACTLY R11: subset poll (wave w polls
//    its 8 producers on a padded 64B line), wave0-consolidated 4x512B
//    8B-atomic store bursts, own-vmcnt drain, flag store; syncA + syncC.

#define B_   32
#define T_   512
#define D_   512
#define H_   1024
#define KTOT 1536
#define N4H  4096
#define NBLK 64
#define NPROD 192
#define NITEM 16384   // 256 tt x 64 n-tiles

typedef __bf16 bf16_t;
typedef __bf16 bf16x8 __attribute__((ext_vector_type(8)));
typedef float f32x4 __attribute__((ext_vector_type(4)));

#define MFMA16(a, b, c) __builtin_amdgcn_mfma_f32_16x16x32_bf16(a, b, c, 0, 0, 0)

// ---------------------------------------------------------------------------
__global__ void wconv_kernel(const float* __restrict__ Wx,
                             const float* __restrict__ Wh,
                             bf16_t* __restrict__ Wt) {
    __shared__ float tile[32][33];
    int k0 = blockIdx.x * 32;
    int n0 = blockIdx.y * 32;
    int tx = threadIdx.x;
    int ty = threadIdx.y;
    for (int i = ty; i < 32; i += 8) {
        int k = k0 + i;
        float v = (k < H_) ? Wh[(size_t)k * N4H + n0 + tx]
                           : Wx[(size_t)(k - H_) * N4H + n0 + tx];
        tile[i][tx] = v;
    }
    __syncthreads();
    for (int i = ty; i < 32; i += 8)
        Wt[(size_t)(n0 + i) * KTOT + k0 + tx] = (bf16_t)tile[tx][i];
}

// ---------------------------------------------------------------------------
// X -> packed uint32 per element: low16 = bf16(hi), high16 = bf16(residual).
__global__ void xconv_kernel(const float4* __restrict__ X,
                             uint4* __restrict__ Xpk) {
    int i = blockIdx.x * blockDim.x + threadIdx.x;
    float4 v = X[i];
    float arr[4] = {v.x, v.y, v.z, v.w};
    unsigned pk[4];
#pragma unroll
    for (int j = 0; j < 4; ++j) {
        bf16_t h = (bf16_t)arr[j];
        bf16_t l = (bf16_t)(arr[j] - (float)h);
        pk[j] = (unsigned)__builtin_bit_cast(unsigned short, h) |
                ((unsigned)__builtin_bit_cast(unsigned short, l) << 16);
    }
    Xpk[i] = make_uint4(pk[0], pk[1], pk[2], pk[3]);
}

// ---------------------------------------------------------------------------
__device__ __forceinline__ void unpack16(const unsigned short* s,
                                         bf16x8* hi, bf16x8* lo) {
#pragma unroll
    for (int j = 0; j < 8; ++j) {
        (*hi)[j] = __builtin_bit_cast(bf16_t, s[2 * j]);
        (*lo)[j] = __builtin_bit_cast(bf16_t, s[2 * j + 1]);
    }
}

// ---------------------------------------------------------------------------
// Unified persistent kernel. XP=1: blocks 0-63 consumer loop (xproj-fed),
// blocks 64-255 xproj producers. XP=0: grid 64, exact R11 in-loop x.
template <int XP>
__global__ __launch_bounds__(512, 1) void lstm_kernel(
    const bf16_t* __restrict__ Wt,
    const unsigned* __restrict__ Xpk,
    float* __restrict__ xproj,
    unsigned* __restrict__ hpk,
    const float* __restrict__ bias,
    const int* __restrict__ seqlen,
    float* __restrict__ out,
    unsigned* __restrict__ flags,
    unsigned* __restrict__ counters) {
    __shared__ float zpart[8][4][32][16];  // 64 KB partial sums
    __shared__ unsigned stage[512];        // 2 KB h-store stage

    const int tid  = threadIdx.x;
    const int w    = tid >> 6;
    const int lane = tid & 63;
    const int quad = lane >> 4;
    const int lcol = lane & 15;

    // ---------------- producer role (XP=1, blocks 64..255) ----------------
    if (XP && (int)blockIdx.x >= NBLK) {
#pragma unroll 1
        for (int item = (int)blockIdx.x - NBLK; item < NITEM; item += NPROD) {
            const int tt = item >> 6;          // 2 timesteps per tt
            const int nt = item & 63;
            const int m0 = tt * 64 + (w >> 2) * 32;
            const int n0 = nt * 64 + (w & 3) * 16;
            const int t0 = tt * 2;
            bf16x8 wr[16];
#pragma unroll
            for (int kk = 0; kk < 16; ++kk)
                wr[kk] = *(const bf16x8*)(Wt + (size_t)(n0 + lcol) * KTOT +
                                          1024 + kk * 32 + quad * 8);
            f32x4 acc0 = {0.f, 0.f, 0.f, 0.f};
            f32x4 acc1 = {0.f, 0.f, 0.f, 0.f};
#pragma unroll 4
            for (int kk = 0; kk < 16; ++kk) {
                union { uint4 q[2]; unsigned short s[16]; } u0, u1;
                const unsigned* p0 =
                    Xpk + ((size_t)lcol * T_ + t0) * D_ + kk * 32 + quad * 8;
                const unsigned* p1 =
                    Xpk + ((size_t)lcol * T_ + t0 + 1) * D_ + kk * 32 + quad * 8;
                u0.q[0] = *(const uint4*)p0;
                u0.q[1] = *(const uint4*)(p0 + 4);
                u1.q[0] = *(const uint4*)p1;
                u1.q[1] = *(const uint4*)(p1 + 4);
                bf16x8 a0h, a0l, a1h, a1l;
                unpack16(u0.s, &a0h, &a0l);
                unpack16(u1.s, &a1h, &a1l);
                acc0 = MFMA16(a0h, wr[kk], acc0);
                acc0 = MFMA16(a0l, wr[kk], acc0);
                acc1 = MFMA16(a1h, wr[kk], acc1);
                acc1 = MFMA16(a1l, wr[kk], acc1);
            }
#pragma unroll
            for (int r = 0; r < 4; ++r) {
                __hip_atomic_store(
                    xproj + (size_t)(m0 + quad * 4 + r) * N4H + n0 + lcol,
                    acc0[r], __ATOMIC_RELAXED, __HIP_MEMORY_SCOPE_AGENT);
                __hip_atomic_store(
                    xproj + (size_t)(m0 + 32 + quad * 4 + r) * N4H + n0 + lcol,
                    acc1[r], __ATOMIC_RELAXED, __HIP_MEMORY_SCOPE_AGENT);
            }
            asm volatile("s_waitcnt vmcnt(0)" ::: "memory");
            __syncthreads();   // all 8 waves' stores drained
            if (tid == 0)
                __hip_atomic_fetch_add(counters + tt, 1u, __ATOMIC_RELAXED,
                                       __HIP_MEMORY_SCOPE_AGENT);
        }
        return;
    }

    // ---------------- consumer / recurrent loop (blocks 0..63) -------------
    const int hc0 = blockIdx.x * 16;
    const int HW_ = 32768;                 // uints per h buffer (B_*H_)

    // Weight fragments: XP=1 -> 16 h-fragments; XP=0 -> R11's 24 (4h+2x).
    bf16x8 wreg[XP ? 16 : 24];
    if (XP) {
#pragma unroll
        for (int g = 0; g < 4; ++g)
#pragma unroll
            for (int it = 0; it < 4; ++it)
                wreg[g * 4 + it] = *(const bf16x8*)(
                    Wt + (size_t)(g * H_ + hc0 + lcol) * KTOT + w * 128 +
                    it * 32 + quad * 8);
    } else {
#pragma unroll
        for (int g = 0; g < 4; ++g)
#pragma unroll
            for (int it = 0; it < 6; ++it) {
                int k = (it < 4) ? (w * 128 + it * 32)
                                 : (1024 + w * 64 + (it - 4) * 32);
                wreg[g * 6 + it] = *(const bf16x8*)(
                    Wt + (size_t)(g * H_ + hc0 + lcol) * KTOT + k + quad * 8);
            }
    }

    // Epilogue mapping: 512 threads = one (batch,col) element each.
    const int eb = tid >> 4, ec = tid & 15;
    const int col = hc0 + ec;
    float creg = 0.f;
    const float b0 = bias[col];
    const float b1 = bias[H_ + col];
    const float b2 = bias[2 * H_ + col];
    const float b3 = bias[3 * H_ + col];
    const int slm1 = seqlen[eb] - 1;
    const int stageIdx = (eb >> 4) * 256 + ((ec >> 3) * 16 + (eb & 15)) * 8 +
                         (ec & 7);
    const int kbB  = (hc0 >> 5) * 1024;
    const int qlo  = (hc0 >> 4) & 1;
    const int QU   = (kbB >> 1) + qlo * 128;
    const int myflag = ((blockIdx.x >> 3) << 4) | (blockIdx.x & 7);
    const unsigned* pollp = flags + w * 16 + (lane & 7);

#pragma unroll 1
    for (int t = 0; t < T_; ++t) {
        const unsigned* hr = hpk + (size_t)(t & 1) * HW_;
        unsigned*       hw = hpk + (size_t)((t + 1) & 1) * HW_;

        f32x4 acc[8];
#pragma unroll
        for (int i = 0; i < 8; ++i) acc[i] = (f32x4){0.f, 0.f, 0.f, 0.f};

        float xp0, xp1, xp2, xp3;
        if (XP) {
            // Gate on producer progress (covers t and t+1), then fetch.
            if ((t & 1) == 0) {
                const unsigned* cp = counters + (t >> 1);
                while (__hip_atomic_load(cp, __ATOMIC_RELAXED,
                                         __HIP_MEMORY_SCOPE_AGENT) < 64u)
                    __builtin_amdgcn_s_sleep(1);
            }
            asm volatile("" ::: "memory");
            const float* xpt = xproj + (size_t)(t * B_ + eb) * N4H + col;
            xp0 = __hip_atomic_load(xpt, __ATOMIC_RELAXED,
                                    __HIP_MEMORY_SCOPE_AGENT);
            xp1 = __hip_atomic_load(xpt + H_, __ATOMIC_RELAXED,
                                    __HIP_MEMORY_SCOPE_AGENT);
            xp2 = __hip_atomic_load(xpt + 2 * H_, __ATOMIC_RELAXED,
                                    __HIP_MEMORY_SCOPE_AGENT);
            xp3 = __hip_atomic_load(xpt + 3 * H_, __ATOMIC_RELAXED,
                                    __HIP_MEMORY_SCOPE_AGENT);
        } else {
            xp0 = xp1 = xp2 = xp3 = 0.f;
            // R11 x part: in-loop, fills the wait window.
#pragma unroll
            for (int itx = 0; itx < 2; ++itx) {
                int kx = w * 64 + itx * 32 + quad * 8;
                union { uint4 q[2]; unsigned short s[16]; } u0, u1;
                const unsigned* p0 = Xpk + ((size_t)lcol * T_ + t) * D_ + kx;
                const unsigned* p1 =
                    Xpk + ((size_t)(lcol + 16) * T_ + t) * D_ + kx;
                u0.q[0] = *(const uint4*)p0;
                u0.q[1] = *(const uint4*)(p0 + 4);
                u1.q[0] = *(const uint4*)p1;
                u1.q[1] = *(const uint4*)(p1 + 4);
                bf16x8 a0h, a0l, a1h, a1l;
                unpack16(u0.s, &a0h, &a0l);
                unpack16(u1.s, &a1h, &a1l);
#pragma unroll
                for (int g = 0; g < 4; ++g) {
                    bf16x8 wv = wreg[g * 6 + 4 + itx];
                    acc[g * 2]     = MFMA16(a0h, wv, acc[g * 2]);
                    acc[g * 2]     = MFMA16(a0l, wv, acc[g * 2]);
                    acc[g * 2 + 1] = MFMA16(a1h, wv, acc[g * 2 + 1]);
                    acc[g * 2 + 1] = MFMA16(a1l, wv, acc[g * 2 + 1]);
                }
            }
        }

        // ---- wait for THIS wave's 8 h-producers only (tight spin) ----
        {
            const unsigned tgt = (unsigned)t;
            for (;;) {
                unsigned v = __hip_atomic_load(pollp, __ATOMIC_RELAXED,
                                               __HIP_MEMORY_SCOPE_AGENT);
                if (__all((int)(v >= tgt))) break;
            }
            asm volatile("" ::: "memory");
        }

        // ---- h part: issue all 8 fragment loads, then unpack + MFMA ----
        union Raw { unsigned long long u[4]; unsigned short s[16]; };
        Raw r[8];
#pragma unroll
        for (int it = 0; it < 4; ++it) {
            const unsigned long long* q = (const unsigned long long*)(
                hr + (w * 4 + it) * 1024 + lane * 8);
#pragma unroll
            for (int j = 0; j < 4; ++j)
                r[it * 2].u[j] = __hip_atomic_load(
                    q + j, __ATOMIC_RELAXED, __HIP_MEMORY_SCOPE_AGENT);
#pragma unroll
            for (int j = 0; j < 4; ++j)
                r[it * 2 + 1].u[j] = __hip_atomic_load(
                    q + 256 + j, __ATOMIC_RELAXED, __HIP_MEMORY_SCOPE_AGENT);
        }
#pragma unroll
        for (int it = 0; it < 4; ++it) {
            bf16x8 a0h, a0l, a1h, a1l;
            unpack16(r[it * 2].s, &a0h, &a0l);
            unpack16(r[it * 2 + 1].s, &a1h, &a1l);
#pragma unroll
            for (int g = 0; g < 4; ++g) {
                bf16x8 wv = XP ? wreg[g * 4 + it] : wreg[g * 6 + it];
                acc[g * 2]     = MFMA16(a0h, wv, acc[g * 2]);
                acc[g * 2]     = MFMA16(a0l, wv, acc[g * 2]);
                acc[g * 2 + 1] = MFMA16(a1h, wv, acc[g * 2 + 1]);
                acc[g * 2 + 1] = MFMA16(a1l, wv, acc[g * 2 + 1]);
            }
        }

#pragma unroll
        for (int g = 0; g < 4; ++g)
#pragma unroll
            for (int r4 = 0; r4 < 4; ++r4) {
                zpart[w][g][quad * 4 + r4][lcol]      = acc[g * 2][r4];
                zpart[w][g][16 + quad * 4 + r4][lcol] = acc[g * 2 + 1][r4];
            }
        __syncthreads();  // A: zpart complete

        // Epilogue (all 512 threads).
        float zi = b0 + xp0, zf = b1 + xp1, zg = b2 + xp2, zo = b3 + xp3;
#pragma unroll
        for (int ss = 0; ss < 8; ++ss) {
            zi += zpart[ss][0][eb][ec];
            zf += zpart[ss][1][eb][ec];
            zg += zpart[ss][2][eb][ec];
            zo += zpart[ss][3][eb][ec];
        }
        float ig = 1.f / (1.f + __expf(-zi));
        float fg = 1.f / (1.f + __expf(-zf));
        float og = 1.f / (1.f + __expf(-zo));
        float gg = 1.f - 2.f / (__expf(2.f * zg) + 1.f);
        creg = fg * creg + ig * gg;
        float hn = og * (1.f - 2.f / (__expf(2.f * creg) + 1.f));
        bf16_t hh = (bf16_t)hn;
        bf16_t hl = (bf16_t)(hn - (float)hh);
        unsigned pk = (unsigned)__builtin_bit_cast(unsigned short, hh) |
                      ((unsigned)__builtin_bit_cast(unsigned short, hl) << 16);
        stage[stageIdx] = pk;
        if (slm1 == t) out[eb * H_ + col] = hn;

        __syncthreads();  // C: stage complete (zpart reads also done)

        // Wave 0 alone: 4 rounds x contiguous 512B of 8B agent atomic
        // stores (R5-identical dst layout), drain OWN vmcnt, post flag.
        if (w == 0) {
            const unsigned long long* sp = (const unsigned long long*)stage;
            unsigned long long* hwu = (unsigned long long*)hw;
#pragma unroll
            for (int j = 0; j < 4; ++j) {
                unsigned long long val = sp[j * 64 + lane];
                __hip_atomic_store(
                    hwu + QU + (j >> 1) * 256 + (j & 1) * 64 + lane, val,
                    __ATOMIC_RELAXED, __HIP_MEMORY_SCOPE_AGENT);
            }
            asm volatile("s_waitcnt vmcnt(0)" ::: "memory");
            if (lane == 0)
                __hip_atomic_store(flags + myflag, (unsigned)(t + 1),
                                   __ATOMIC_RELAXED, __HIP_MEMORY_SCOPE_AGENT);
        }
    }
}

// ---------------------------------------------------------------------------
extern "C" void kernel_launch(void* const* d_in, const int* in_sizes, int n_in,
                              void* d_out, int out_size, void* d_ws, size_t ws_size,
                              hipStream_t stream) {
    const float* inputs = (const float*)d_in[0];
    const int*   seqlen = (const int*)d_in[1];
    const float* Wx     = (const float*)d_in[2];
    const float* Wh     = (const float*)d_in[3];
    const float* bias   = (const float*)d_in[4];
    float* out = (float*)d_out;

    char* ws = (char*)d_ws;
    size_t o = 0;
    bf16_t*   Wt    = (bf16_t*)(ws + o);   o += (size_t)N4H * KTOT * 2;   // 12.6MB
    unsigned* Xpk   = (unsigned*)(ws + o); o += (size_t)B_ * T_ * D_ * 4; // 33.6MB
    unsigned* hpk   = (unsigned*)(ws + o); o += (size_t)2 * B_ * H_ * 4;  // 256KB
    unsigned* flags = (unsigned*)(ws + o); o += 4096;
    unsigned* cnts  = (unsigned*)(ws + o); o += 4096;
    float*    xproj = (float*)(ws + o);
    const size_t NEED = o + (size_t)B_ * T_ * N4H * 4;  // +256MB
    const bool use_xp = ws_size >= NEED;

    wconv_kernel<<<dim3(48, 128), dim3(32, 8), 0, stream>>>(Wx, Wh, Wt);
    xconv_kernel<<<(B_ * T_ * D_ / 4) / 256, 256, 0, stream>>>(
        (const float4*)inputs, (uint4*)Xpk);
    hipMemsetAsync(hpk, 0, (size_t)B_ * H_ * 4, stream);  // ping p=0 zeros
    hipMemsetAsync(flags, 0, 8192, stream);               // flags + counters

    if (use_xp)
        lstm_kernel<1><<<NBLK + NPROD, 512, 0, stream>>>(
            Wt, Xpk, xproj, hpk, bias, seqlen, out, flags, cnts);
    else
        lstm_kernel<0><<<NBLK, 512, 0, stream>>>(
            Wt, Xpk, xproj, hpk, bias, seqlen, out, flags, cnts);
}